// Round 2
// baseline (304.618 us; speedup 1.0000x reference)
//
#include <hip/hip_runtime.h>
#include <hip/hip_bf16.h>
#include <math.h>

#define PATCH 41
#define PP 1681          // 41*41
#define NB 8
#define KS 16            // pooling kernel size
#define STRIDE 10
#define PAD 4
#define HSTRIDE 33       // 32 cells (8 bins x 4 ox) + 1 pad to break bank alignment
#define HSIZE (PATCH * HSTRIDE)   // 1353

__device__ __forceinline__ int imax(int a, int b) { return a > b ? a : b; }
__device__ __forceinline__ int imin(int a, int b) { return a < b ? a : b; }

// u[k] = xc2[k]/8; u[i]*u[j] == pk[i][j] EXACTLY (xc2 are half-integers,
// products have <=8 significant bits -> no rounding).
__device__ __forceinline__ float tri16(int k) {
    return (8.0f - fabsf((float)k + 0.5f - 8.0f)) * 0.125f;
}

// block-wide sum over 256 threads (4 waves). All threads must call.
__device__ __forceinline__ float block_sum(float v, float* s_red, int t) {
    #pragma unroll
    for (int o = 32; o > 0; o >>= 1) v += __shfl_xor(v, o);
    if ((t & 63) == 0) s_red[t >> 6] = v;
    __syncthreads();
    float total = s_red[0] + s_red[1] + s_red[2] + s_red[3];
    __syncthreads();
    return total;
}

__global__ __launch_bounds__(256, 6) void sift_desc_kernel(
        const float* __restrict__ x,   // [N,1,41,41]
        const float* __restrict__ gk,  // [41,41]
        const float* __restrict__ pk,  // [16,16] (unused: recomputed exactly)
        float* __restrict__ out)       // [N,128]
{
    const int patch = blockIdx.x;
    const int t = threadIdx.x;

    __shared__ float s_x[PP];
    __shared__ float s_H[HSIZE];   // [row i][bin*4 + ox], horizontally pooled
    __shared__ float s_red[4];

    // ---- stage 0: load patch, zero H ----
    const float* xp = x + (size_t)patch * PP;
    for (int p = t; p < PP; p += 256) s_x[p] = xp[p];
    for (int c = t; c < HSIZE; c += 256) s_H[c] = 0.0f;
    __syncthreads();

    // ---- stage 1: gradients, fast atan2 binning, horizontal-pool scatter ----
    const float TWO_PI = 6.28318530717958647692f;
    const float FOUR_OVER_PI = 1.27323954473516268615f;
    for (int p = t; p < PP; p += 256) {
        int i = p / PATCH;
        int j = p - i * PATCH;
        float xl = s_x[p - (j > 0)];
        float xr = s_x[p + (j < PATCH - 1)];
        float xu = s_x[p - (i > 0) * PATCH];
        float xd = s_x[p + (i < PATCH - 1) * PATCH];
        float gxv = xr - xl;
        float gyv = xd - xu;
        float X = gxv + 1e-10f;
        float mag = sqrtf(gxv * gxv + gyv * gyv + 1e-10f) * gk[p];

        // fast atan2(gyv, X): octant reduce + deg-11 minimax (err ~1e-6 rad)
        float ax = fabsf(X), ay = fabsf(gyv);
        float mx = fmaxf(ax, ay), mn = fminf(ax, ay);
        float r = mn * __builtin_amdgcn_rcpf(mx);
        float r2 = r * r;
        float a = fmaf(r2, -0.01172120f, 0.05265332f);
        a = fmaf(r2, a, -0.11643287f);
        a = fmaf(r2, a, 0.19354346f);
        a = fmaf(r2, a, -0.33262347f);
        a = fmaf(r2, a, 0.99997726f);
        a *= r;
        if (ay > ax)   a = 1.57079632679489661923f - a;
        if (X < 0.0f)  a = 3.14159265358979323846f - a;
        if (gyv < 0.0f) a = -a;

        float o = (a + TWO_PI) * FOUR_OVER_PI;   // in (4,12]
        float f = floorf(o);
        float w1 = o - f;
        int b0 = ((int)f) & 7;
        int b1 = (b0 + 1) & 7;
        float m0v = (1.0f - w1) * mag;
        float m1v = w1 * mag;

        // columns j is covered by ox windows [ox*10-4, ox*10+11]
        int ox_lo = imax(0, (j - 2) / 10);
        int ox_hi = imin(3, (j + 4) / 10);
        int row = i * HSTRIDE;
        for (int ox = ox_lo; ox <= ox_hi; ++ox) {
            int kx = j - ox * STRIDE + PAD;     // in [0,15]
            float u = tri16(kx);
            atomicAdd(&s_H[row + b0 * 4 + ox], u * m0v);
            atomicAdd(&s_H[row + b1 * 4 + ox], u * m1v);
        }
    }
    __syncthreads();

    // ---- stage 2: vertical 16-tap gather (128 active threads) ----
    float v = 0.0f;
    if (t < 128) {
        int b = t >> 4;
        int cell = t & 15;
        int oy = cell >> 2, ox = cell & 3;
        int iy0 = oy * STRIDE - PAD;
        int ky_lo = imax(0, -iy0);
        int ky_hi = imin(KS - 1, PATCH - 1 - iy0);
        int col = b * 4 + ox;
        float acc = 0.0f;
        for (int ky = ky_lo; ky <= ky_hi; ++ky) {
            acc = fmaf(tri16(ky), s_H[(iy0 + ky) * HSTRIDE + col], acc);
        }
        v = acc;
    }

    // ---- stage 3: L2 -> clip 0.2 -> L2 -> L1 -> sqrt ----
    float sumsq = block_sum(v * v, s_red, t);
    v *= 1.0f / fmaxf(sqrtf(sumsq), 1e-12f);
    v = fminf(fmaxf(v, 0.0f), 0.2f);

    float sumsq2 = block_sum(v * v, s_red, t);
    v *= 1.0f / fmaxf(sqrtf(sumsq2), 1e-12f);

    float l1 = block_sum(v, s_red, t);   // v >= 0 after clip
    v = v / fmaxf(l1, 1e-12f);

    if (t < 128) out[(size_t)patch * 128 + t] = sqrtf(v + 1e-10f);
}

extern "C" void kernel_launch(void* const* d_in, const int* in_sizes, int n_in,
                              void* d_out, int out_size, void* d_ws, size_t ws_size,
                              hipStream_t stream) {
    const float* x  = (const float*)d_in[0];
    const float* gk = (const float*)d_in[1];
    const float* pk = (const float*)d_in[2];
    float* out = (float*)d_out;
    const int n = in_sizes[0] / PP;   // 8192 patches
    sift_desc_kernel<<<n, 256, 0, stream>>>(x, gk, pk, out);
}

// Round 3
// 156.299 us; speedup vs baseline: 1.9489x; 1.9489x over previous
//
#include <hip/hip_runtime.h>
#include <hip/hip_bf16.h>
#include <math.h>

#define PATCH 41
#define PP 1681          // 41*41
#define NB 8
#define KS 16            // pooling kernel size
#define STRIDE 10
#define PAD 4
#define HSTRIDE 33       // 32 cells (8 bins x 4 ox) + 1 pad to break bank alignment

__device__ __forceinline__ int imax(int a, int b) { return a > b ? a : b; }
__device__ __forceinline__ int imin(int a, int b) { return a < b ? a : b; }

// u[k] = xc2[k]/8; u[i]*u[j] == pk[i][j] EXACTLY (xc2 are half-integers,
// products have <=8 significant bits -> no rounding).
__device__ __forceinline__ float tri16(int k) {
    return (8.0f - fabsf((float)k + 0.5f - 8.0f)) * 0.125f;
}

// block-wide sum over 256 threads (4 waves). All threads must call.
__device__ __forceinline__ float block_sum(float v, float* s_red, int t) {
    #pragma unroll
    for (int o = 32; o > 0; o >>= 1) v += __shfl_xor(v, o);
    if ((t & 63) == 0) s_red[t >> 6] = v;
    __syncthreads();
    float total = s_red[0] + s_red[1] + s_red[2] + s_red[3];
    __syncthreads();
    return total;
}

__global__ __launch_bounds__(256, 6) void sift_desc_kernel(
        const float* __restrict__ x,   // [N,1,41,41]
        const float* __restrict__ gk,  // [41,41]
        const float* __restrict__ pk,  // [16,16] (unused: recomputed exactly)
        float* __restrict__ out)       // [N,128]
{
    const int patch = blockIdx.x;
    const int t = threadIdx.x;

    __shared__ float s_x[PP];
    __shared__ float s_H[PATCH * HSTRIDE];  // [row][bin*4 + ox]
    __shared__ float s_red[4];

    // ---- stage 0: load patch into LDS ----
    const float* xp = x + (size_t)patch * PP;
    for (int p = t; p < PP; p += 256) s_x[p] = xp[p];
    __syncthreads();

    // ---- stage 1: one thread per (row, ox-window). Gather 16 columns,
    //      accumulate 8 angular bins in registers. No atomics. ----
    const float TWO_PI = 6.28318530717958647692f;
    const float FOUR_OVER_PI = 1.27323954473516268615f;

    if (t < PATCH * 4) {
        const int row = t >> 2;        // 0..40
        const int ox  = t & 3;
        const int jbase = ox * STRIDE - PAD;
        const float* gkrow = gk + row * PATCH;
        const int rbase = row * PATCH;

        float acc[NB];
        #pragma unroll
        for (int b = 0; b < NB; ++b) acc[b] = 0.0f;

        #pragma unroll 4
        for (int kx = 0; kx < KS; ++kx) {
            int j = jbase + kx;
            int jc = imin(imax(j, 0), PATCH - 1);
            int p = rbase + jc;
            float xl = s_x[p - (jc > 0)];
            float xr = s_x[p + (jc < PATCH - 1)];
            float xu = s_x[p - (row > 0) * PATCH];
            float xd = s_x[p + (row < PATCH - 1) * PATCH];
            float gxv = xr - xl;
            float gyv = xd - xu;
            float X = gxv + 1e-10f;
            float mag = sqrtf(gxv * gxv + gyv * gyv + 1e-10f) * gkrow[jc] * tri16(kx);
            mag = (j == jc) ? mag : 0.0f;   // window column outside patch

            // fast atan2(gyv, X): octant reduce + deg-11 minimax (err ~1e-6 rad)
            float ax = fabsf(X), ay = fabsf(gyv);
            float mx = fmaxf(ax, ay), mn = fminf(ax, ay);
            float r = mn * __builtin_amdgcn_rcpf(mx);
            float r2 = r * r;
            float a = fmaf(r2, -0.01172120f, 0.05265332f);
            a = fmaf(r2, a, -0.11643287f);
            a = fmaf(r2, a, 0.19354346f);
            a = fmaf(r2, a, -0.33262347f);
            a = fmaf(r2, a, 0.99997726f);
            a *= r;
            if (ay > ax)    a = 1.57079632679489661923f - a;
            if (X < 0.0f)   a = 3.14159265358979323846f - a;
            if (gyv < 0.0f) a = -a;

            float o = (a + TWO_PI) * FOUR_OVER_PI;   // in (4,12]
            float f = floorf(o);
            float w1 = o - f;
            int b0 = ((int)f) & 7;
            int b1 = (b0 + 1) & 7;
            float m0v = (1.0f - w1) * mag;
            float m1v = w1 * mag;

            #pragma unroll
            for (int b = 0; b < NB; ++b) {
                float add = ((b == b0) ? m0v : 0.0f) + ((b == b1) ? m1v : 0.0f);
                acc[b] += add;
            }
        }

        // each (row, b, ox) cell owned by exactly this thread
        #pragma unroll
        for (int b = 0; b < NB; ++b)
            s_H[row * HSTRIDE + b * 4 + ox] = acc[b];
    }
    __syncthreads();

    // ---- stage 2: vertical 16-tap gather (128 active threads) ----
    float v = 0.0f;
    if (t < 128) {
        int b = t >> 4;
        int cell = t & 15;
        int oy = cell >> 2, ox = cell & 3;
        int iy0 = oy * STRIDE - PAD;
        int ky_lo = imax(0, -iy0);
        int ky_hi = imin(KS - 1, PATCH - 1 - iy0);
        int col = b * 4 + ox;
        float acc = 0.0f;
        for (int ky = ky_lo; ky <= ky_hi; ++ky) {
            acc = fmaf(tri16(ky), s_H[(iy0 + ky) * HSTRIDE + col], acc);
        }
        v = acc;
    }

    // ---- stage 3: L2 -> clip 0.2 -> L2 -> L1 -> sqrt ----
    float sumsq = block_sum(v * v, s_red, t);
    v *= 1.0f / fmaxf(sqrtf(sumsq), 1e-12f);
    v = fminf(fmaxf(v, 0.0f), 0.2f);

    float sumsq2 = block_sum(v * v, s_red, t);
    v *= 1.0f / fmaxf(sqrtf(sumsq2), 1e-12f);

    float l1 = block_sum(v, s_red, t);   // v >= 0 after clip
    v = v / fmaxf(l1, 1e-12f);

    if (t < 128) out[(size_t)patch * 128 + t] = sqrtf(v + 1e-10f);
}

extern "C" void kernel_launch(void* const* d_in, const int* in_sizes, int n_in,
                              void* d_out, int out_size, void* d_ws, size_t ws_size,
                              hipStream_t stream) {
    const float* x  = (const float*)d_in[0];
    const float* gk = (const float*)d_in[1];
    const float* pk = (const float*)d_in[2];
    float* out = (float*)d_out;
    const int n = in_sizes[0] / PP;   // 8192 patches
    sift_desc_kernel<<<n, 256, 0, stream>>>(x, gk, pk, out);
}

// Round 4
// 133.111 us; speedup vs baseline: 2.2884x; 1.1742x over previous
//
#include <hip/hip_runtime.h>
#include <hip/hip_bf16.h>
#include <math.h>

#define PATCH 41
#define PP 1681          // 41*41
#define NB 8
#define KS 16            // pooling kernel size
#define STRIDE 10
#define PAD 4
#define HSTRIDE 33       // 32 cells (8 bins x 4 ox) + 1 pad to break bank alignment
#define NTHREADS 192     // 3 waves

__device__ __forceinline__ int imax(int a, int b) { return a > b ? a : b; }
__device__ __forceinline__ int imin(int a, int b) { return a < b ? a : b; }

// u[k] = xc2[k]/8; u[i]*u[j] == pk[i][j] EXACTLY (xc2 are half-integers,
// products have <=8 significant bits -> no rounding).
__device__ __forceinline__ constexpr float tri16(int k) {
    float d = (float)k + 0.5f - 8.0f;
    float a = d < 0.0f ? -d : d;
    return (8.0f - a) * 0.125f;
}

// block-wide sum over 192 threads (3 waves). All threads must call.
__device__ __forceinline__ float block_sum(float v, float* s_red, int t) {
    #pragma unroll
    for (int o = 32; o > 0; o >>= 1) v += __shfl_xor(v, o);
    if ((t & 63) == 0) s_red[t >> 6] = v;
    __syncthreads();
    float total = s_red[0] + s_red[1] + s_red[2];
    __syncthreads();
    return total;
}

__global__ __launch_bounds__(NTHREADS, 8) void sift_desc_kernel(
        const float* __restrict__ x,   // [N,1,41,41]
        const float* __restrict__ gk,  // [41,41]
        const float* __restrict__ pk,  // [16,16] (unused: recomputed exactly)
        float* __restrict__ out)       // [N,128]
{
    const int patch = blockIdx.x;
    const int t = threadIdx.x;

    __shared__ float s_x[PP];
    __shared__ float s_gk[PP];
    __shared__ float s_H[PATCH * HSTRIDE];  // [row][bin*4 + ox]
    __shared__ float s_red[3];

    // ---- stage 0: load patch + gaussian into LDS ----
    const float* xp = x + (size_t)patch * PP;
    for (int p = t; p < PP; p += NTHREADS) {
        s_x[p] = xp[p];
        s_gk[p] = gk[p];
    }
    __syncthreads();

    // ---- stage 1: one thread per (row, ox-window). Gather 16 columns,
    //      accumulate 8 angular bins in registers. No atomics. ----
    const float TWO_PI = 6.28318530717958647692f;
    const float FOUR_OVER_PI = 1.27323954473516268615f;

    if (t < PATCH * 4) {
        const int row = t >> 2;        // 0..40
        const int ox  = t & 3;
        const int jbase = ox * STRIDE - PAD;
        const int rbase = row * PATCH;
        const int up = (row > 0) ? -PATCH : 0;       // hoisted row offsets
        const int dn = (row < PATCH - 1) ? PATCH : 0;

        float acc[NB];
        #pragma unroll
        for (int b = 0; b < NB; ++b) acc[b] = 0.0f;

        #pragma unroll
        for (int kx = 0; kx < KS; ++kx) {
            const float u = tri16(kx);          // compile-time constant
            int j = jbase + kx;
            int jc = imin(imax(j, 0), PATCH - 1);
            int p = rbase + jc;
            float xl = s_x[p - (jc > 0)];
            float xr = s_x[p + (jc < PATCH - 1)];
            float xu = s_x[p + up];
            float xd = s_x[p + dn];
            float gxv = xr - xl;
            float gyv = xd - xu;
            float X = gxv + 1e-10f;
            float mag = sqrtf(gxv * gxv + gyv * gyv + 1e-10f) * s_gk[p] * u;
            mag = (j == jc) ? mag : 0.0f;   // window column outside patch

            // fast atan2(gyv, X): octant reduce + deg-11 minimax (err ~1e-6 rad)
            float ax = fabsf(X), ay = fabsf(gyv);
            float mx = fmaxf(ax, ay), mn = fminf(ax, ay);
            float r = mn * __builtin_amdgcn_rcpf(mx);
            float r2 = r * r;
            float a = fmaf(r2, -0.01172120f, 0.05265332f);
            a = fmaf(r2, a, -0.11643287f);
            a = fmaf(r2, a, 0.19354346f);
            a = fmaf(r2, a, -0.33262347f);
            a = fmaf(r2, a, 0.99997726f);
            a *= r;
            if (ay > ax)    a = 1.57079632679489661923f - a;
            if (X < 0.0f)   a = 3.14159265358979323846f - a;
            if (gyv < 0.0f) a = -a;

            float o = (a + TWO_PI) * FOUR_OVER_PI;   // in (4,12]
            float f = floorf(o);
            float w1 = o - f;
            int b0 = ((int)f) & 7;
            float m0v = (1.0f - w1) * mag;   // -> bin b0
            float m1v = w1 * mag;            // -> bin (b0+1)&7

            // even/odd scatter tree: exactly one even bin and one odd bin
            // receive a contribution per pixel.
            const bool podd = (b0 & 1) != 0;
            float ve = podd ? m1v : m0v;     // to even bin ie
            float vo = podd ? m0v : m1v;     // to odd bin io
            int ie = (b0 + (b0 & 1)) & 7;    // in {0,2,4,6}
            int io = b0 | 1;                 // in {1,3,5,7}

            float eA = (ie & 4) ? 0.0f : ve;
            float eB = (ie & 4) ? ve : 0.0f;
            acc[0] += (ie & 2) ? 0.0f : eA;
            acc[2] += (ie & 2) ? eA : 0.0f;
            acc[4] += (ie & 2) ? 0.0f : eB;
            acc[6] += (ie & 2) ? eB : 0.0f;

            float oA = (io & 4) ? 0.0f : vo;
            float oB = (io & 4) ? vo : 0.0f;
            acc[1] += (io & 2) ? 0.0f : oA;
            acc[3] += (io & 2) ? oA : 0.0f;
            acc[5] += (io & 2) ? 0.0f : oB;
            acc[7] += (io & 2) ? oB : 0.0f;
        }

        // each (row, b, ox) cell owned by exactly this thread
        #pragma unroll
        for (int b = 0; b < NB; ++b)
            s_H[row * HSTRIDE + b * 4 + ox] = acc[b];
    }
    __syncthreads();

    // ---- stage 2: vertical 16-tap gather (128 active threads) ----
    float v = 0.0f;
    if (t < 128) {
        int b = t >> 4;
        int cell = t & 15;
        int oy = cell >> 2, ox = cell & 3;
        int iy0 = oy * STRIDE - PAD;
        int ky_lo = imax(0, -iy0);
        int ky_hi = imin(KS - 1, PATCH - 1 - iy0);
        int col = b * 4 + ox;
        float acc = 0.0f;
        for (int ky = ky_lo; ky <= ky_hi; ++ky) {
            acc = fmaf(tri16(ky), s_H[(iy0 + ky) * HSTRIDE + col], acc);
        }
        v = acc;
    }

    // ---- stage 3: L2 -> clip 0.2 -> L2 -> L1 -> sqrt ----
    float sumsq = block_sum(v * v, s_red, t);
    v *= 1.0f / fmaxf(sqrtf(sumsq), 1e-12f);
    v = fminf(fmaxf(v, 0.0f), 0.2f);

    float sumsq2 = block_sum(v * v, s_red, t);
    v *= 1.0f / fmaxf(sqrtf(sumsq2), 1e-12f);

    float l1 = block_sum(v, s_red, t);   // v >= 0 after clip
    v = v / fmaxf(l1, 1e-12f);

    if (t < 128) out[(size_t)patch * 128 + t] = sqrtf(v + 1e-10f);
}

extern "C" void kernel_launch(void* const* d_in, const int* in_sizes, int n_in,
                              void* d_out, int out_size, void* d_ws, size_t ws_size,
                              hipStream_t stream) {
    const float* x  = (const float*)d_in[0];
    const float* gk = (const float*)d_in[1];
    const float* pk = (const float*)d_in[2];
    float* out = (float*)d_out;
    const int n = in_sizes[0] / PP;   // 8192 patches
    sift_desc_kernel<<<n, NTHREADS, 0, stream>>>(x, gk, pk, out);
}